// Round 16
// baseline (553.631 us; speedup 1.0000x reference)
//
#include <hip/hip_runtime.h>

#define NN 524288
#define NE 2097152
#define NG 16384
#define CDIM 3539
#define PDIM 384
#define GH 64
#define GE 128
#define HIDD 256
#define KD (GE + CDIM + PDIM)  // 4051
#define KP 4096                // padded K stride (bf16 elems)

typedef short bf16x8 __attribute__((ext_vector_type(8)));
typedef unsigned short u16x8 __attribute__((ext_vector_type(8)));
typedef float f32x4 __attribute__((ext_vector_type(4)));

__device__ inline unsigned short f2bf(float f) {
    unsigned int u = __float_as_uint(f);
    u += 0x7FFF + ((u >> 16) & 1);  // RNE
    return (unsigned short)(u >> 16);
}

// ---------------- init: idg=0, zero sums ----------------
__global__ void k_init(int* __restrict__ idg, float* __restrict__ sums) {
    int i = blockIdx.x * blockDim.x + threadIdx.x;
    if (i < NN) idg[i] = 0;
    if (i < NG * GH) sums[i] = 0.0f;
}

// ---------------- in-degree histogram over col; eseq = within-node slot ----------------
__global__ void k_deg(const int* __restrict__ ei, int* __restrict__ idg,
                      int* __restrict__ eseq) {
    int e = blockIdx.x * blockDim.x + threadIdx.x;
    eseq[e] = atomicAdd(&idg[ei[NE + e]], 1);
}

// ---------------- dinv, f2a = {dinv*x, dinv}, integer edge counts ----------------
__global__ void k_prep(const float* __restrict__ node_x, const int* __restrict__ idg,
                       float2* __restrict__ f2a, int* __restrict__ ecnt) {
    int n = blockIdx.x * blockDim.x + threadIdx.x;
    int c = idg[n];
    float di = rsqrtf((float)(c + 1));  // +1 self-loop
    f2a[n] = make_float2(di * node_x[n], di);
    ecnt[n] = c;
}

// ---------------- cnt[g] via binary search on sorted batch ----------------
__global__ void k_cnt(const int* __restrict__ batch, float* __restrict__ cnt) {
    int g = blockIdx.x * 256 + threadIdx.x;  // NG threads
    int lo = 0, hi = NN;
    while (lo < hi) { int mid = (lo + hi) >> 1; if (batch[mid] < g) lo = mid + 1; else hi = mid; }
    int lo2 = lo, hi2 = NN;
    while (lo2 < hi2) { int mid = (lo2 + hi2) >> 1; if (batch[mid] < g + 1) lo2 = mid + 1; else hi2 = mid; }
    cnt[g] = (float)(lo2 - lo);
}

// ---------------- 3-kernel exclusive scan of ecnt[NN] -> offs[NN+1] ----------------
__global__ void k_scan1(const int* __restrict__ ecnt, int* __restrict__ bsum) {
    __shared__ int ls[256];
    int t = threadIdx.x;
    ls[t] = ecnt[blockIdx.x * 256 + t];
    __syncthreads();
    for (int d = 128; d > 0; d >>= 1) { if (t < d) ls[t] += ls[t + d]; __syncthreads(); }
    if (t == 0) bsum[blockIdx.x] = ls[0];
}

__global__ void k_scan2(int* __restrict__ bsum) {  // 1 block, 2048 elems
    __shared__ int ls[256];
    int t = threadIdx.x;
    int loc[8]; int s = 0;
#pragma unroll
    for (int i = 0; i < 8; i++) { loc[i] = bsum[t * 8 + i]; s += loc[i]; }
    ls[t] = s; __syncthreads();
    for (int d = 1; d < 256; d <<= 1) {
        int add = (t >= d) ? ls[t - d] : 0; __syncthreads();
        ls[t] += add; __syncthreads();
    }
    int run = ls[t] - s;  // exclusive
#pragma unroll
    for (int i = 0; i < 8; i++) { int tmp = loc[i]; bsum[t * 8 + i] = run; run += tmp; }
}

__global__ void k_scan3(const int* __restrict__ ecnt, const int* __restrict__ bsum,
                        int* __restrict__ offs) {
    __shared__ int ls[256];
    int t = threadIdx.x, n = blockIdx.x * 256 + t;
    int v = ecnt[n];
    ls[t] = v; __syncthreads();
    for (int d = 1; d < 256; d <<= 1) {
        int add = (t >= d) ? ls[t - d] : 0; __syncthreads();
        ls[t] += add; __syncthreads();
    }
    offs[n] = bsum[blockIdx.x] + ls[t] - v;
    if (n == 0) offs[NN] = NE;
}

// ---------------- CSR fill: atomic-free (slot from eseq) ----------------
__global__ void k_fill(const int* __restrict__ ei, const int* __restrict__ offs,
                       const int* __restrict__ eseq, int* __restrict__ csr) {
    int e = blockIdx.x * 256 + threadIdx.x;
    int r = ei[e], c = ei[NE + e];
    csr[offs[c] + eseq[e]] = r;
}

// ---------------- pass A: s[c] = dinv_c*(sum f2a[csr].x + dinv_c x_c); sd={s,dinv} ------
__global__ void k_sg(const int* __restrict__ offs, const int* __restrict__ csr,
                     const float2* __restrict__ f2a, float2* __restrict__ sd) {
    int n = blockIdx.x * 256 + threadIdx.x;
    int a = offs[n], b = offs[n + 1];
    float2 me = f2a[n];
    float sum = me.x;
    for (int e = a; e < b; e += 4) {
#pragma unroll
        for (int i = 0; i < 4; i++) {
            int ee = e + i;
            int r = csr[min(ee, b - 1)];
            float v = f2a[r].x;
            sum += (ee < b) ? v : 0.0f;
        }
    }
    sd[n] = make_float2(me.y * sum, me.y);
}

// ================= FUSED: batched gather -> W2 MFMA -> relu -> segmented pool ============
__global__ __launch_bounds__(256) void k_gx2(
        const int* __restrict__ offs, const int* __restrict__ csr,
        const float2* __restrict__ sd, const float* __restrict__ W1,
        const float* __restrict__ b1, const unsigned short* __restrict__ W2T,
        const float* __restrict__ b2, const int* __restrict__ batch,
        float* __restrict__ sums) {
    __shared__ unsigned short aggs[64][72];
    __shared__ float x2s[64][73];   // stride 73: breaks 4-way phase-2 write conflict
    __shared__ int bloc[64];
    int t = threadIdx.x;
    int wv = t >> 6, lane = t & 63;
    int n0 = blockIdx.x * 64;
    int nw = n0 + wv * 16;
    if (t < 64) bloc[t] = batch[n0 + t];
    float w1j = W1[lane], b1j = b1[lane];
    int nl = nw + (lane & 15);
    int aL = offs[nl], bndL = offs[nl + 1];
    float2 sdL = sd[nl];

    int base   = __shfl(aL, 0, 64);     // offs[nw]
    int endAll = __shfl(bndL, 15, 64);  // offs[nw+16]

#define LOADB(dst, bs) do { int en = (bs) + lane;                        \
    dst = make_float2(0.0f, 0.0f);                                       \
    if (en < endAll) dst = sd[csr[en]]; } while (0)

    int bstart = base;
    float2 vcur, vnxt;
    LOADB(vcur, bstart);
    LOADB(vnxt, bstart + 64);

    for (int i = 0; i < 16; i++) {
        int a    = __shfl(aL, i, 64);
        int bnd  = __shfl(bndL, i, 64);
        float sx = __shfl(sdL.x, i, 64);
        float sy = __shfl(sdL.y, i, 64);
        float acc = sy * fmaxf(fmaf(sx, w1j, b1j), 0.0f);  // self-loop
        for (int e = a; e < bnd; ++e) {
            int slot = e - bstart;
            if (slot >= 64) {            // wave-uniform batch advance
                bstart += 64;
                slot -= 64;
                vcur = vnxt;
                LOADB(vnxt, bstart + 64);
            }
            float vx = __shfl(vcur.x, slot, 64);
            float vy = __shfl(vcur.y, slot, 64);
            acc = fmaf(vy, fmaxf(fmaf(vx, w1j, b1j), 0.0f), acc);
        }
        aggs[wv * 16 + i][lane] = f2bf(sy * acc);
    }
#undef LOADB

    __syncthreads();
    int lg = lane >> 4, lr = lane & 15;
    bf16x8 a0 = *reinterpret_cast<const bf16x8*>(&aggs[wv * 16 + lr][lg * 8]);
    bf16x8 a1 = *reinterpret_cast<const bf16x8*>(&aggs[wv * 16 + lr][32 + lg * 8]);
    f32x4 acc4[4];
#pragma unroll
    for (int jt = 0; jt < 4; jt++) acc4[jt] = (f32x4){0.f, 0.f, 0.f, 0.f};
#pragma unroll
    for (int jt = 0; jt < 4; jt++) {
        bf16x8 b0 = *reinterpret_cast<const bf16x8*>(W2T + (jt * 16 + lr) * GH + lg * 8);
        bf16x8 b1v = *reinterpret_cast<const bf16x8*>(W2T + (jt * 16 + lr) * GH + 32 + lg * 8);
        acc4[jt] = __builtin_amdgcn_mfma_f32_16x16x32_bf16(a0, b0, acc4[jt], 0, 0, 0);
        acc4[jt] = __builtin_amdgcn_mfma_f32_16x16x32_bf16(a1, b1v, acc4[jt], 0, 0, 0);
    }
#pragma unroll
    for (int jt = 0; jt < 4; jt++) {
        float bj = b2[jt * 16 + lr];
#pragma unroll
        for (int r = 0; r < 4; r++)
            x2s[wv * 16 + lg * 4 + r][jt * 16 + lr] = fmaxf(acc4[jt][r] + bj, 0.0f);
    }
    __syncthreads();
    for (int i = wv; i < 64; i += 4) {
        bool isStart = (i == 0) || (bloc[i] != bloc[i - 1]);
        if (isStart) {
            int g = bloc[i];
            float s = 0.0f;
            int k = i;
            do { s += x2s[k][lane]; k++; } while (k < 64 && bloc[k] == g);
            atomicAdd(&sums[g * GH + lane], s);
        }
    }
}

// ---------------- per-graph: pooled = sums/cnt; gemb = pooled @ Wg + bg ----------------
__global__ void k_graph(const float* __restrict__ sums, const float* __restrict__ cnt,
                        const float* __restrict__ Wg, const float* __restrict__ bg,
                        float* __restrict__ gemb) {
    __shared__ float wgs[GH * GE];   // 32 KB
    __shared__ float ps[4 * GH];
    int t = threadIdx.x;
    for (int i = t; i < GH * GE; i += 256) wgs[i] = Wg[i];
    int gid = blockIdx.x * 256 + t;
    int g = gid >> 6, j = t & 63, w = t >> 6;
    float c = fmaxf(cnt[g], 1.0f);
    ps[t] = sums[g * GH + j] / c;
    __syncthreads();
    float o0 = bg[j], o1 = bg[GH + j];
#pragma unroll
    for (int k = 0; k < GH; k++) {
        float p = ps[w * GH + k];
        o0 = fmaf(p, wgs[k * GE + j], o0);
        o1 = fmaf(p, wgs[k * GE + GH + j], o1);
    }
    gemb[g * GE + j] = o0;
    gemb[g * GE + GH + j] = o1;
}

// ---------------- transpose+convert Wf1 -> WT bf16; block 1024 builds W2T ----------------
__global__ void k_wt(const float* __restrict__ Wf1, unsigned short* __restrict__ WT,
                     const float* __restrict__ W2, unsigned short* __restrict__ W2T) {
    if (blockIdx.x == 1024) {  // W2T[j][k] = bf16(W2[k][j]), 64x64
        int t = threadIdx.x;
        for (int i = 0; i < 16; i++) {
            int idx = t * 16 + i;
            int j = idx >> 6, k = idx & 63;
            W2T[j * GH + k] = f2bf(W2[k * GH + j]);
        }
        return;
    }
    __shared__ float tl[32][33];
    int bk = blockIdx.x & 127;
    int bn = blockIdx.x >> 7;
    int tx = threadIdx.x & 31, ty = threadIdx.x >> 5;  // 32 x 8
    int k0 = bk * 32, n0 = bn * 32;
#pragma unroll
    for (int i = 0; i < 4; i++) {
        int k = k0 + ty + i * 8;
        tl[ty + i * 8][tx] = (k < KD) ? Wf1[k * HIDD + n0 + tx] : 0.0f;
    }
    __syncthreads();
#pragma unroll
    for (int i = 0; i < 4; i++) {
        int n = n0 + ty + i * 8;
        WT[n * KP + k0 + tx] = f2bf(tl[tx][ty + i * 8]);
    }
}

// ---------------- build combined [NG][KP] bf16: guard-free paths for all pure regions ----
__global__ void k_comb(const float* __restrict__ gemb, const float* __restrict__ comp,
                       const float* __restrict__ prot, unsigned short* __restrict__ comb) {
    int idx = blockIdx.x * 256 + threadIdx.x;   // NG*512 threads, 8 elems each
    int g = idx >> 9;
    int k0 = (idx & 511) * 8;
    u16x8 r;
    float v[8];
    if (k0 + 8 <= GE) {                                   // pure gemb (boundary 8-aligned)
        __builtin_memcpy(v, gemb + (size_t)g * GE + k0, 32);
#pragma unroll
        for (int i = 0; i < 8; i++) r[i] = f2bf(v[i]);
    } else if (k0 >= GE && k0 + 8 <= GE + CDIM) {         // pure comp
        __builtin_memcpy(v, comp + (size_t)g * CDIM + (k0 - GE), 32);
#pragma unroll
        for (int i = 0; i < 8; i++) r[i] = f2bf(v[i]);
    } else if (k0 >= GE + CDIM && k0 + 8 <= KD) {         // pure prot
        __builtin_memcpy(v, prot + (size_t)g * PDIM + (k0 - GE - CDIM), 32);
#pragma unroll
        for (int i = 0; i < 8; i++) r[i] = f2bf(v[i]);
    } else if (k0 >= KD) {                                // pure pad
#pragma unroll
        for (int i = 0; i < 8; i++) r[i] = 0;
    } else {                                              // 2 straddling chunks per row
#pragma unroll
        for (int i = 0; i < 8; i++) {
            int k = k0 + i;
            float x = 0.0f;
            if (k < GE) x = gemb[g * GE + k];
            else if (k < GE + CDIM) x = comp[(size_t)g * CDIM + (k - GE)];
            else if (k < KD) x = prot[g * PDIM + (k - GE - CDIM)];
            r[i] = f2bf(x);
        }
    }
    *reinterpret_cast<u16x8*>(comb + (size_t)idx * 8) = r;
}

// ---------------- MFMA head GEMM: LDS-staged (R9-proven), g-tile 16 -> grid 1024 --------
// 4 blocks/CU (36 KB LDS): 2x the co-resident blocks of the R9 shape to hide the
// per-step vmcnt(0) barrier drain. Wave = 64n x 16g (acc[4][1]).
typedef const __attribute__((address_space(1))) void gas_void;
typedef __attribute__((address_space(3))) void las_void;

__global__ __launch_bounds__(256) void k_gemm_mfma(
        const unsigned short* __restrict__ WT, const unsigned short* __restrict__ comb,
        const float* __restrict__ bf1, const float* __restrict__ Wf2,
        const float* __restrict__ bf2, float* __restrict__ out) {
    __shared__ unsigned short ldsA[2][256 * 32];  // 16 KB each
    __shared__ unsigned short ldsB[2][16 * 32];   // 1 KB each
    __shared__ float red[16];
    int t = threadIdx.x;
    int wv = t >> 6, lane = t & 63;
    int lg = lane >> 4, lr = lane & 15;
    int g0 = blockIdx.x * 16;
    int nbase = wv * 64;

    int rowp = lane >> 2;        // 0..15 (row within 16-row staging chunk)
    int kp = (lane & 3) * 8;     // 0,8,16,24 (k within 32-k step)

    if (t < 16) red[t] = 0.0f;

    f32x4 acc[4];
#pragma unroll
    for (int i = 0; i < 4; i++) acc[i] = (f32x4){0.f, 0.f, 0.f, 0.f};

#define STAGE(buf, k0) do {                                                                  \
    _Pragma("unroll")                                                                        \
    for (int i = 0; i < 4; i++)                                                              \
        __builtin_amdgcn_global_load_lds(                                                    \
            (gas_void*)(WT + (size_t)(wv * 64 + i * 16 + rowp) * KP + (k0) + kp),            \
            (las_void*)(&ldsA[buf][(wv * 64 + i * 16) * 32]), 16, 0, 0);                     \
    if (wv == 0)                                                                             \
        __builtin_amdgcn_global_load_lds(                                                    \
            (gas_void*)(comb + (size_t)(g0 + rowp) * KP + (k0) + kp),                        \
            (las_void*)(&ldsB[buf][0]), 16, 0, 0);                                           \
} while (0)

    STAGE(0, 0);
    __syncthreads();
#pragma unroll 1
    for (int s = 0; s < 128; ++s) {
        int cur = s & 1;
        if (s < 127) STAGE(cur ^ 1, (s + 1) * 32);
        bf16x8 a[4], b;
#pragma unroll
        for (int nt = 0; nt < 4; nt++)
            a[nt] = *reinterpret_cast<const bf16x8*>(&ldsA[cur][(nbase + nt * 16 + lr) * 32 + lg * 8]);
        b = *reinterpret_cast<const bf16x8*>(&ldsB[cur][lr * 32 + lg * 8]);
#pragma unroll
        for (int nt = 0; nt < 4; nt++)
            acc[nt] = __builtin_amdgcn_mfma_f32_16x16x32_bf16(a[nt], b, acc[nt], 0, 0, 0);
        __syncthreads();  // drains staging (vmcnt) + frag reads before buffer reuse
    }
#undef STAGE

    float bf2c = bf2[0];
    {
        float pv = 0.0f;
#pragma unroll
        for (int nt = 0; nt < 4; nt++) {
            int nb = nbase + nt * 16 + lg * 4;
#pragma unroll
            for (int r = 0; r < 4; r++) {
                float h = fmaxf(acc[nt][r] + bf1[nb + r], 0.0f);
                pv = fmaf(h, Wf2[nb + r], pv);
            }
        }
        pv += __shfl_xor(pv, 16);
        pv += __shfl_xor(pv, 32);
        if (lane < 16) atomicAdd(&red[lane], pv);
    }
    __syncthreads();
    if (t < 16) out[g0 + t] = 1.0f / (1.0f + expf(-(red[t] + bf2c)));
}

extern "C" void kernel_launch(void* const* d_in, const int* in_sizes, int n_in,
                              void* d_out, int out_size, void* d_ws, size_t ws_size,
                              hipStream_t stream) {
    const float* node_x = (const float*)d_in[0];
    const float* comp   = (const float*)d_in[1];
    const float* prot   = (const float*)d_in[2];
    const int*   ei     = (const int*)d_in[3];
    const int*   batch  = (const int*)d_in[4];
    const float* W1  = (const float*)d_in[5];
    const float* b1  = (const float*)d_in[6];
    const float* W2  = (const float*)d_in[7];
    const float* b2  = (const float*)d_in[8];
    const float* Wg  = (const float*)d_in[9];
    const float* bg  = (const float*)d_in[10];
    const float* Wf1 = (const float*)d_in[11];
    const float* bf1 = (const float*)d_in[12];
    const float* Wf2 = (const float*)d_in[13];
    const float* bf2 = (const float*)d_in[14];
    float* out = (float*)d_out;

    // -------- workspace layout (region A [0,134MB) becomes comb at k_comb) ----------------
    char* W = (char*)d_ws;
    unsigned short* comb = (unsigned short*)W;
    int*    idg     = (int*)(W + 0);            // NN int (edge counts; dead after k_prep)
    float2* f2a     = (float2*)(W + 2097152);   // NN float2
    float2* sd      = (float2*)(W + 6291456);   // NN float2
    int*    ecnt    = (int*)(W + 10485760);     // NN int
    int*    offs    = (int*)(W + 12582912);     // NN+1 int
    int*    bsum    = (int*)(W + 16777728);     // 2048 int
    int*    csr     = (int*)(W + 16786432);     // NE int
    float*  sums    = (float*)(W + 25175040);   // NG*64 f32
    float*  cnt     = (float*)(W + 29369344);   // NG f32
    int*    eseq    = (int*)(W + 33554432);     // NE int (within-node slot)
    // Region B/C (live to the end):
    float*  gemb    = (float*)(W + 134217728);              // NG*128 f32
    unsigned short* WT  = (unsigned short*)(W + 142606336); // 256*KP bf16
    unsigned short* W2T = (unsigned short*)(W + 144703488); // 64*64 bf16

    k_init<<<4096, 256, 0, stream>>>(idg, sums);
    k_wt<<<1025, 256, 0, stream>>>(Wf1, WT, W2, W2T);  // FIRST: W2T/WT ready before use
    k_deg<<<NE / 256, 256, 0, stream>>>(ei, idg, eseq);
    k_prep<<<NN / 256, 256, 0, stream>>>(node_x, idg, f2a, ecnt);
    k_cnt<<<NG / 256, 256, 0, stream>>>(batch, cnt);
    k_scan1<<<NN / 256, 256, 0, stream>>>(ecnt, bsum);
    k_scan2<<<1, 256, 0, stream>>>(bsum);
    k_scan3<<<NN / 256, 256, 0, stream>>>(ecnt, bsum, offs);
    k_fill<<<NE / 256, 256, 0, stream>>>(ei, offs, eseq, csr);
    k_sg<<<NN / 256, 256, 0, stream>>>(offs, csr, f2a, sd);
    k_gx2<<<NN / 64, 256, 0, stream>>>(offs, csr, sd, W1, b1, W2T, b2, batch, sums);
    k_graph<<<NG * GH / 256, 256, 0, stream>>>(sums, cnt, Wg, bg, gemb);
    k_comb<<<NG * 512 / 256, 256, 0, stream>>>(gemb, comp, prot, comb);
    k_gemm_mfma<<<NG / 16, 256, 0, stream>>>(WT, comb, bf1, Wf2, bf2, out);
}

// Round 17
// 510.832 us; speedup vs baseline: 1.0838x; 1.0838x over previous
//
#include <hip/hip_runtime.h>

#define NN 524288
#define NE 2097152
#define NG 16384
#define CDIM 3539
#define PDIM 384
#define GH 64
#define GE 128
#define HIDD 256
#define KD (GE + CDIM + PDIM)  // 4051
#define KP 4096                // padded K stride (bf16 elems)

typedef short bf16x8 __attribute__((ext_vector_type(8)));
typedef unsigned short u16x8 __attribute__((ext_vector_type(8)));
typedef float f32x4 __attribute__((ext_vector_type(4)));

__device__ inline unsigned short f2bf(float f) {
    unsigned int u = __float_as_uint(f);
    u += 0x7FFF + ((u >> 16) & 1);  // RNE
    return (unsigned short)(u >> 16);
}

// ---------------- init: idg=0, zero sums ----------------
__global__ void k_init(int* __restrict__ idg, float* __restrict__ sums) {
    int i = blockIdx.x * blockDim.x + threadIdx.x;
    if (i < NN) idg[i] = 0;
    if (i < NG * GH) sums[i] = 0.0f;
}

// ---------------- in-degree histogram over col; eseq = within-node slot ----------------
__global__ void k_deg(const int* __restrict__ ei, int* __restrict__ idg,
                      int* __restrict__ eseq) {
    int e = blockIdx.x * blockDim.x + threadIdx.x;
    eseq[e] = atomicAdd(&idg[ei[NE + e]], 1);
}

// ---------------- dinv, f2a = {dinv*x, dinv}, integer edge counts ----------------
__global__ void k_prep(const float* __restrict__ node_x, const int* __restrict__ idg,
                       float2* __restrict__ f2a, int* __restrict__ ecnt) {
    int n = blockIdx.x * blockDim.x + threadIdx.x;
    int c = idg[n];
    float di = rsqrtf((float)(c + 1));  // +1 self-loop
    f2a[n] = make_float2(di * node_x[n], di);
    ecnt[n] = c;
}

// ---------------- cnt[g] via binary search on sorted batch ----------------
__global__ void k_cnt(const int* __restrict__ batch, float* __restrict__ cnt) {
    int g = blockIdx.x * 256 + threadIdx.x;  // NG threads
    int lo = 0, hi = NN;
    while (lo < hi) { int mid = (lo + hi) >> 1; if (batch[mid] < g) lo = mid + 1; else hi = mid; }
    int lo2 = lo, hi2 = NN;
    while (lo2 < hi2) { int mid = (lo2 + hi2) >> 1; if (batch[mid] < g + 1) lo2 = mid + 1; else hi2 = mid; }
    cnt[g] = (float)(lo2 - lo);
}

// ---------------- 3-kernel exclusive scan of ecnt[NN] -> offs[NN+1] ----------------
__global__ void k_scan1(const int* __restrict__ ecnt, int* __restrict__ bsum) {
    __shared__ int ls[256];
    int t = threadIdx.x;
    ls[t] = ecnt[blockIdx.x * 256 + t];
    __syncthreads();
    for (int d = 128; d > 0; d >>= 1) { if (t < d) ls[t] += ls[t + d]; __syncthreads(); }
    if (t == 0) bsum[blockIdx.x] = ls[0];
}

__global__ void k_scan2(int* __restrict__ bsum) {  // 1 block, 2048 elems
    __shared__ int ls[256];
    int t = threadIdx.x;
    int loc[8]; int s = 0;
#pragma unroll
    for (int i = 0; i < 8; i++) { loc[i] = bsum[t * 8 + i]; s += loc[i]; }
    ls[t] = s; __syncthreads();
    for (int d = 1; d < 256; d <<= 1) {
        int add = (t >= d) ? ls[t - d] : 0; __syncthreads();
        ls[t] += add; __syncthreads();
    }
    int run = ls[t] - s;  // exclusive
#pragma unroll
    for (int i = 0; i < 8; i++) { int tmp = loc[i]; bsum[t * 8 + i] = run; run += tmp; }
}

__global__ void k_scan3(const int* __restrict__ ecnt, const int* __restrict__ bsum,
                        int* __restrict__ offs) {
    __shared__ int ls[256];
    int t = threadIdx.x, n = blockIdx.x * 256 + t;
    int v = ecnt[n];
    ls[t] = v; __syncthreads();
    for (int d = 1; d < 256; d <<= 1) {
        int add = (t >= d) ? ls[t - d] : 0; __syncthreads();
        ls[t] += add; __syncthreads();
    }
    offs[n] = bsum[blockIdx.x] + ls[t] - v;
    if (n == 0) offs[NN] = NE;
}

// ---------------- CSR fill: atomic-free (slot from eseq) ----------------
__global__ void k_fill(const int* __restrict__ ei, const int* __restrict__ offs,
                       const int* __restrict__ eseq, int* __restrict__ csr) {
    int e = blockIdx.x * 256 + threadIdx.x;
    int r = ei[e], c = ei[NE + e];
    csr[offs[c] + eseq[e]] = r;
}

// ---------------- pass A: s[c] = dinv_c*(sum f2a[csr].x + dinv_c x_c); unroll-8 ----------
__global__ void k_sg(const int* __restrict__ offs, const int* __restrict__ csr,
                     const float2* __restrict__ f2a, float2* __restrict__ sd) {
    int n = blockIdx.x * 256 + threadIdx.x;
    int a = offs[n], b = offs[n + 1];
    float2 me = f2a[n];
    float sum = me.x;
    for (int e = a; e < b; e += 8) {
#pragma unroll
        for (int i = 0; i < 8; i++) {
            int ee = e + i;
            int r = csr[min(ee, b - 1)];
            float v = f2a[r].x;
            sum += (ee < b) ? v : 0.0f;
        }
    }
    sd[n] = make_float2(me.y * sum, me.y);
}

// ================= FUSED: batched gather -> W2 MFMA -> relu -> segmented pool ============
// Edge phase unrolled by 2: two edges per iteration (independent shfl+FMA chains).
__global__ __launch_bounds__(256) void k_gx2(
        const int* __restrict__ offs, const int* __restrict__ csr,
        const float2* __restrict__ sd, const float* __restrict__ W1,
        const float* __restrict__ b1, const unsigned short* __restrict__ W2T,
        const float* __restrict__ b2, const int* __restrict__ batch,
        float* __restrict__ sums) {
    __shared__ unsigned short aggs[64][72];
    __shared__ float x2s[64][73];   // stride 73: breaks 4-way phase-2 write conflict
    __shared__ int bloc[64];
    int t = threadIdx.x;
    int wv = t >> 6, lane = t & 63;
    int n0 = blockIdx.x * 64;
    int nw = n0 + wv * 16;
    if (t < 64) bloc[t] = batch[n0 + t];
    float w1j = W1[lane], b1j = b1[lane];
    int nl = nw + (lane & 15);
    int aL = offs[nl], bndL = offs[nl + 1];
    float2 sdL = sd[nl];

    int base   = __shfl(aL, 0, 64);     // offs[nw]
    int endAll = __shfl(bndL, 15, 64);  // offs[nw+16]

#define LOADB(dst, bs) do { int en = (bs) + lane;                        \
    dst = make_float2(0.0f, 0.0f);                                       \
    if (en < endAll) dst = sd[csr[en]]; } while (0)

    int bstart = base;
    float2 vcur, vnxt;
    LOADB(vcur, bstart);
    LOADB(vnxt, bstart + 64);

    for (int i = 0; i < 16; i++) {
        int a    = __shfl(aL, i, 64);
        int bnd  = __shfl(bndL, i, 64);
        float sx = __shfl(sdL.x, i, 64);
        float sy = __shfl(sdL.y, i, 64);
        float acc = sy * fmaxf(fmaf(sx, w1j, b1j), 0.0f);  // self-loop
        for (int e = a; e < bnd; e += 2) {
            int slot = e - bstart;      // wave-uniform, <= 65 by induction
            if (slot >= 64) {           // uniform batch advance
                bstart += 64;
                slot -= 64;
                vcur = vnxt;
                LOADB(vnxt, bstart + 64);
            }
            // edge 0 (slot in [0,63])
            float vx0 = __shfl(vcur.x, slot, 64);
            float vy0 = __shfl(vcur.y, slot, 64);
            acc = fmaf(vy0, fmaxf(fmaf(vx0, w1j, b1j), 0.0f), acc);
            // edge 1 (slot+1 may be 64 -> lane 0 of vnxt); uniform select
            if (e + 1 < bnd) {
                int s1 = slot + 1;
                float vx1 = (s1 < 64) ? __shfl(vcur.x, s1 & 63, 64) : __shfl(vnxt.x, 0, 64);
                float vy1 = (s1 < 64) ? __shfl(vcur.y, s1 & 63, 64) : __shfl(vnxt.y, 0, 64);
                acc = fmaf(vy1, fmaxf(fmaf(vx1, w1j, b1j), 0.0f), acc);
            }
        }
        aggs[wv * 16 + i][lane] = f2bf(sy * acc);
    }
#undef LOADB

    __syncthreads();
    int lg = lane >> 4, lr = lane & 15;
    bf16x8 a0 = *reinterpret_cast<const bf16x8*>(&aggs[wv * 16 + lr][lg * 8]);
    bf16x8 a1 = *reinterpret_cast<const bf16x8*>(&aggs[wv * 16 + lr][32 + lg * 8]);
    f32x4 acc4[4];
#pragma unroll
    for (int jt = 0; jt < 4; jt++) acc4[jt] = (f32x4){0.f, 0.f, 0.f, 0.f};
#pragma unroll
    for (int jt = 0; jt < 4; jt++) {
        bf16x8 b0 = *reinterpret_cast<const bf16x8*>(W2T + (jt * 16 + lr) * GH + lg * 8);
        bf16x8 b1v = *reinterpret_cast<const bf16x8*>(W2T + (jt * 16 + lr) * GH + 32 + lg * 8);
        acc4[jt] = __builtin_amdgcn_mfma_f32_16x16x32_bf16(a0, b0, acc4[jt], 0, 0, 0);
        acc4[jt] = __builtin_amdgcn_mfma_f32_16x16x32_bf16(a1, b1v, acc4[jt], 0, 0, 0);
    }
#pragma unroll
    for (int jt = 0; jt < 4; jt++) {
        float bj = b2[jt * 16 + lr];
#pragma unroll
        for (int r = 0; r < 4; r++)
            x2s[wv * 16 + lg * 4 + r][jt * 16 + lr] = fmaxf(acc4[jt][r] + bj, 0.0f);
    }
    __syncthreads();
    for (int i = wv; i < 64; i += 4) {
        bool isStart = (i == 0) || (bloc[i] != bloc[i - 1]);
        if (isStart) {
            int g = bloc[i];
            float s = 0.0f;
            int k = i;
            do { s += x2s[k][lane]; k++; } while (k < 64 && bloc[k] == g);
            atomicAdd(&sums[g * GH + lane], s);
        }
    }
}

// ---------------- per-graph: pooled = sums/cnt; gemb = pooled @ Wg + bg ----------------
__global__ void k_graph(const float* __restrict__ sums, const float* __restrict__ cnt,
                        const float* __restrict__ Wg, const float* __restrict__ bg,
                        float* __restrict__ gemb) {
    __shared__ float wgs[GH * GE];   // 32 KB
    __shared__ float ps[4 * GH];
    int t = threadIdx.x;
    for (int i = t; i < GH * GE; i += 256) wgs[i] = Wg[i];
    int gid = blockIdx.x * 256 + t;
    int g = gid >> 6, j = t & 63, w = t >> 6;
    float c = fmaxf(cnt[g], 1.0f);
    ps[t] = sums[g * GH + j] / c;
    __syncthreads();
    float o0 = bg[j], o1 = bg[GH + j];
#pragma unroll
    for (int k = 0; k < GH; k++) {
        float p = ps[w * GH + k];
        o0 = fmaf(p, wgs[k * GE + j], o0);
        o1 = fmaf(p, wgs[k * GE + GH + j], o1);
    }
    gemb[g * GE + j] = o0;
    gemb[g * GE + GH + j] = o1;
}

// ---------------- transpose+convert Wf1 -> WT bf16; block 1024 builds W2T ----------------
__global__ void k_wt(const float* __restrict__ Wf1, unsigned short* __restrict__ WT,
                     const float* __restrict__ W2, unsigned short* __restrict__ W2T) {
    if (blockIdx.x == 1024) {  // W2T[j][k] = bf16(W2[k][j]), 64x64
        int t = threadIdx.x;
        for (int i = 0; i < 16; i++) {
            int idx = t * 16 + i;
            int j = idx >> 6, k = idx & 63;
            W2T[j * GH + k] = f2bf(W2[k * GH + j]);
        }
        return;
    }
    __shared__ float tl[32][33];
    int bk = blockIdx.x & 127;
    int bn = blockIdx.x >> 7;
    int tx = threadIdx.x & 31, ty = threadIdx.x >> 5;  // 32 x 8
    int k0 = bk * 32, n0 = bn * 32;
#pragma unroll
    for (int i = 0; i < 4; i++) {
        int k = k0 + ty + i * 8;
        tl[ty + i * 8][tx] = (k < KD) ? Wf1[k * HIDD + n0 + tx] : 0.0f;
    }
    __syncthreads();
#pragma unroll
    for (int i = 0; i < 4; i++) {
        int n = n0 + ty + i * 8;
        WT[n * KP + k0 + tx] = f2bf(tl[tx][ty + i * 8]);
    }
}

// ---------------- build combined [NG][KP] bf16: guard-free paths for all pure regions ----
__global__ void k_comb(const float* __restrict__ gemb, const float* __restrict__ comp,
                       const float* __restrict__ prot, unsigned short* __restrict__ comb) {
    int idx = blockIdx.x * 256 + threadIdx.x;   // NG*512 threads, 8 elems each
    int g = idx >> 9;
    int k0 = (idx & 511) * 8;
    u16x8 r;
    float v[8];
    if (k0 + 8 <= GE) {                                   // pure gemb (boundary 8-aligned)
        __builtin_memcpy(v, gemb + (size_t)g * GE + k0, 32);
#pragma unroll
        for (int i = 0; i < 8; i++) r[i] = f2bf(v[i]);
    } else if (k0 >= GE && k0 + 8 <= GE + CDIM) {         // pure comp
        __builtin_memcpy(v, comp + (size_t)g * CDIM + (k0 - GE), 32);
#pragma unroll
        for (int i = 0; i < 8; i++) r[i] = f2bf(v[i]);
    } else if (k0 >= GE + CDIM && k0 + 8 <= KD) {         // pure prot
        __builtin_memcpy(v, prot + (size_t)g * PDIM + (k0 - GE - CDIM), 32);
#pragma unroll
        for (int i = 0; i < 8; i++) r[i] = f2bf(v[i]);
    } else if (k0 >= KD) {                                // pure pad
#pragma unroll
        for (int i = 0; i < 8; i++) r[i] = 0;
    } else {                                              // 2 straddling chunks per row
#pragma unroll
        for (int i = 0; i < 8; i++) {
            int k = k0 + i;
            float x = 0.0f;
            if (k < GE) x = gemb[g * GE + k];
            else if (k < GE + CDIM) x = comp[(size_t)g * CDIM + (k - GE)];
            else if (k < KD) x = prot[g * PDIM + (k - GE - CDIM)];
            r[i] = f2bf(x);
        }
    }
    *reinterpret_cast<u16x8*>(comb + (size_t)idx * 8) = r;
}

// ---------------- MFMA head GEMM: LDS-staged (R9-proven, 256n x 32g), BK=32, dbuf --------
typedef const __attribute__((address_space(1))) void gas_void;
typedef __attribute__((address_space(3))) void las_void;

__global__ __launch_bounds__(256) void k_gemm_mfma(
        const unsigned short* __restrict__ WT, const unsigned short* __restrict__ comb,
        const float* __restrict__ bf1, const float* __restrict__ Wf2,
        const float* __restrict__ bf2, float* __restrict__ out) {
    __shared__ unsigned short ldsA[2][256 * 32];  // 16 KB each
    __shared__ unsigned short ldsB[2][32 * 32];   // 2 KB each
    __shared__ float red[32];
    int t = threadIdx.x;
    int wv = t >> 6, lane = t & 63;
    int lg = lane >> 4, lr = lane & 15;
    int g0 = blockIdx.x * 32;
    int nbase = wv * 64;

    int rowp = lane >> 2;        // 0..15 (row within 16-row staging chunk)
    int kp = (lane & 3) * 8;     // 0,8,16,24 (k within 32-k step)

    if (t < 32) red[t] = 0.0f;

    f32x4 acc[4][2];
#pragma unroll
    for (int i = 0; i < 4; i++)
#pragma unroll
        for (int j = 0; j < 2; j++) acc[i][j] = (f32x4){0.f, 0.f, 0.f, 0.f};

#define STAGE(buf, k0) do {                                                                  \
    _Pragma("unroll")                                                                        \
    for (int i = 0; i < 4; i++)                                                              \
        __builtin_amdgcn_global_load_lds(                                                    \
            (gas_void*)(WT + (size_t)(wv * 64 + i * 16 + rowp) * KP + (k0) + kp),            \
            (las_void*)(&ldsA[buf][(wv * 64 + i * 16) * 32]), 16, 0, 0);                     \
    if (wv < 2)                                                                              \
        __builtin_amdgcn_global_load_lds(                                                    \
            (gas_void*)(comb + (size_t)(g0 + wv * 16 + rowp) * KP + (k0) + kp),              \
            (las_void*)(&ldsB[buf][(wv * 16) * 32]), 16, 0, 0);                              \
} while (0)

    STAGE(0, 0);
    __syncthreads();
#pragma unroll 1
    for (int s = 0; s < 128; ++s) {
        int cur = s & 1;
        if (s < 127) STAGE(cur ^ 1, (s + 1) * 32);
        bf16x8 a[4], b[2];
#pragma unroll
        for (int nt = 0; nt < 4; nt++)
            a[nt] = *reinterpret_cast<const bf16x8*>(&ldsA[cur][(nbase + nt * 16 + lr) * 32 + lg * 8]);
#pragma unroll
        for (int gt = 0; gt < 2; gt++)
            b[gt] = *reinterpret_cast<const bf16x8*>(&ldsB[cur][(gt * 16 + lr) * 32 + lg * 8]);
#pragma unroll
        for (int nt = 0; nt < 4; nt++)
#pragma unroll
            for (int gt = 0; gt < 2; gt++)
                acc[nt][gt] = __builtin_amdgcn_mfma_f32_16x16x32_bf16(a[nt], b[gt], acc[nt][gt], 0, 0, 0);
        __syncthreads();  // drains staging (vmcnt) + frag reads before buffer reuse
    }
#undef STAGE

    float bf2c = bf2[0];
#pragma unroll
    for (int gt = 0; gt < 2; gt++) {
        float pv = 0.0f;
#pragma unroll
        for (int nt = 0; nt < 4; nt++) {
            int nb = nbase + nt * 16 + lg * 4;
#pragma unroll
            for (int r = 0; r < 4; r++) {
                float h = fmaxf(acc[nt][gt][r] + bf1[nb + r], 0.0f);
                pv = fmaf(h, Wf2[nb + r], pv);
            }
        }
        pv += __shfl_xor(pv, 16);
        pv += __shfl_xor(pv, 32);
        if (lane < 16) atomicAdd(&red[gt * 16 + lane], pv);
    }
    __syncthreads();
    if (t < 32) out[g0 + t] = 1.0f / (1.0f + expf(-(red[t] + bf2c)));
}

extern "C" void kernel_launch(void* const* d_in, const int* in_sizes, int n_in,
                              void* d_out, int out_size, void* d_ws, size_t ws_size,
                              hipStream_t stream) {
    const float* node_x = (const float*)d_in[0];
    const float* comp   = (const float*)d_in[1];
    const float* prot   = (const float*)d_in[2];
    const int*   ei     = (const int*)d_in[3];
    const int*   batch  = (const int*)d_in[4];
    const float* W1  = (const float*)d_in[5];
    const float* b1  = (const float*)d_in[6];
    const float* W2  = (const float*)d_in[7];
    const float* b2  = (const float*)d_in[8];
    const float* Wg  = (const float*)d_in[9];
    const float* bg  = (const float*)d_in[10];
    const float* Wf1 = (const float*)d_in[11];
    const float* bf1 = (const float*)d_in[12];
    const float* Wf2 = (const float*)d_in[13];
    const float* bf2 = (const float*)d_in[14];
    float* out = (float*)d_out;

    // -------- workspace layout (region A [0,134MB) becomes comb at k_comb) ----------------
    char* W = (char*)d_ws;
    unsigned short* comb = (unsigned short*)W;
    int*    idg     = (int*)(W + 0);            // NN int (edge counts; dead after k_prep)
    float2* f2a     = (float2*)(W + 2097152);   // NN float2
    float2* sd      = (float2*)(W + 6291456);   // NN float2
    int*    ecnt    = (int*)(W + 10485760);     // NN int
    int*    offs    = (int*)(W + 12582912);     // NN+1 int
    int*    bsum    = (int*)(W + 16777728);     // 2048 int
    int*    csr     = (int*)(W + 16786432);     // NE int
    float*  sums    = (float*)(W + 25175040);   // NG*64 f32
    float*  cnt     = (float*)(W + 29369344);   // NG f32
    int*    eseq    = (int*)(W + 33554432);     // NE int (within-node slot)
    // Region B/C (live to the end):
    float*  gemb    = (float*)(W + 134217728);              // NG*128 f32
    unsigned short* WT  = (unsigned short*)(W + 142606336); // 256*KP bf16
    unsigned short* W2T = (unsigned short*)(W + 144703488); // 64*64 bf16

    k_init<<<4096, 256, 0, stream>>>(idg, sums);
    k_wt<<<1025, 256, 0, stream>>>(Wf1, WT, W2, W2T);  // FIRST: W2T/WT ready before use
    k_deg<<<NE / 256, 256, 0, stream>>>(ei, idg, eseq);
    k_prep<<<NN / 256, 256, 0, stream>>>(node_x, idg, f2a, ecnt);
    k_cnt<<<NG / 256, 256, 0, stream>>>(batch, cnt);
    k_scan1<<<NN / 256, 256, 0, stream>>>(ecnt, bsum);
    k_scan2<<<1, 256, 0, stream>>>(bsum);
    k_scan3<<<NN / 256, 256, 0, stream>>>(ecnt, bsum, offs);
    k_fill<<<NE / 256, 256, 0, stream>>>(ei, offs, eseq, csr);
    k_sg<<<NN / 256, 256, 0, stream>>>(offs, csr, f2a, sd);
    k_gx2<<<NN / 64, 256, 0, stream>>>(offs, csr, sd, W1, b1, W2T, b2, batch, sums);
    k_graph<<<NG * GH / 256, 256, 0, stream>>>(sums, cnt, Wg, bg, gemb);
    k_comb<<<NG * 512 / 256, 256, 0, stream>>>(gemb, comp, prot, comb);
    k_gemm_mfma<<<NG / 32, 256, 0, stream>>>(WT, comb, bf1, Wf2, bf2, out);
}

// Round 18
// 468.307 us; speedup vs baseline: 1.1822x; 1.0908x over previous
//
#include <hip/hip_runtime.h>

#define NN 524288
#define NE 2097152
#define NG 16384
#define CDIM 3539
#define PDIM 384
#define GH 64
#define GE 128
#define HIDD 256
#define KD (GE + CDIM + PDIM)  // 4051
#define KP 4096                // padded K stride (bf16 elems)

typedef short bf16x8 __attribute__((ext_vector_type(8)));
typedef unsigned short u16x8 __attribute__((ext_vector_type(8)));
typedef float f32x4 __attribute__((ext_vector_type(4)));

__device__ inline unsigned short f2bf(float f) {
    unsigned int u = __float_as_uint(f);
    u += 0x7FFF + ((u >> 16) & 1);  // RNE
    return (unsigned short)(u >> 16);
}

// ---------------- init: idg=0, zero sums ----------------
__global__ void k_init(int* __restrict__ idg, float* __restrict__ sums) {
    int i = blockIdx.x * blockDim.x + threadIdx.x;
    if (i < NN) idg[i] = 0;
    if (i < NG * GH) sums[i] = 0.0f;
}

// ---------------- in-degree histogram over col; eseq = within-node slot ----------------
__global__ void k_deg(const int* __restrict__ ei, int* __restrict__ idg,
                      int* __restrict__ eseq) {
    int e = blockIdx.x * blockDim.x + threadIdx.x;
    eseq[e] = atomicAdd(&idg[ei[NE + e]], 1);
}

// ---------------- dinv, f2a = {dinv*x, dinv}, integer edge counts ----------------
__global__ void k_prep(const float* __restrict__ node_x, const int* __restrict__ idg,
                       float2* __restrict__ f2a, int* __restrict__ ecnt) {
    int n = blockIdx.x * blockDim.x + threadIdx.x;
    int c = idg[n];
    float di = rsqrtf((float)(c + 1));  // +1 self-loop
    f2a[n] = make_float2(di * node_x[n], di);
    ecnt[n] = c;
}

// ---------------- cnt[g] via binary search on sorted batch ----------------
__global__ void k_cnt(const int* __restrict__ batch, float* __restrict__ cnt) {
    int g = blockIdx.x * 256 + threadIdx.x;  // NG threads
    int lo = 0, hi = NN;
    while (lo < hi) { int mid = (lo + hi) >> 1; if (batch[mid] < g) lo = mid + 1; else hi = mid; }
    int lo2 = lo, hi2 = NN;
    while (lo2 < hi2) { int mid = (lo2 + hi2) >> 1; if (batch[mid] < g + 1) lo2 = mid + 1; else hi2 = mid; }
    cnt[g] = (float)(lo2 - lo);
}

// ---------------- 3-kernel exclusive scan of ecnt[NN] -> offs[NN+1] ----------------
__global__ void k_scan1(const int* __restrict__ ecnt, int* __restrict__ bsum) {
    __shared__ int ls[256];
    int t = threadIdx.x;
    ls[t] = ecnt[blockIdx.x * 256 + t];
    __syncthreads();
    for (int d = 128; d > 0; d >>= 1) { if (t < d) ls[t] += ls[t + d]; __syncthreads(); }
    if (t == 0) bsum[blockIdx.x] = ls[0];
}

__global__ void k_scan2(int* __restrict__ bsum) {  // 1 block, 2048 elems
    __shared__ int ls[256];
    int t = threadIdx.x;
    int loc[8]; int s = 0;
#pragma unroll
    for (int i = 0; i < 8; i++) { loc[i] = bsum[t * 8 + i]; s += loc[i]; }
    ls[t] = s; __syncthreads();
    for (int d = 1; d < 256; d <<= 1) {
        int add = (t >= d) ? ls[t - d] : 0; __syncthreads();
        ls[t] += add; __syncthreads();
    }
    int run = ls[t] - s;  // exclusive
#pragma unroll
    for (int i = 0; i < 8; i++) { int tmp = loc[i]; bsum[t * 8 + i] = run; run += tmp; }
}

__global__ void k_scan3(const int* __restrict__ ecnt, const int* __restrict__ bsum,
                        int* __restrict__ offs) {
    __shared__ int ls[256];
    int t = threadIdx.x, n = blockIdx.x * 256 + t;
    int v = ecnt[n];
    ls[t] = v; __syncthreads();
    for (int d = 1; d < 256; d <<= 1) {
        int add = (t >= d) ? ls[t - d] : 0; __syncthreads();
        ls[t] += add; __syncthreads();
    }
    offs[n] = bsum[blockIdx.x] + ls[t] - v;
    if (n == 0) offs[NN] = NE;
}

// ---------------- CSR fill: atomic-free (slot from eseq) ----------------
__global__ void k_fill(const int* __restrict__ ei, const int* __restrict__ offs,
                       const int* __restrict__ eseq, int* __restrict__ csr) {
    int e = blockIdx.x * 256 + threadIdx.x;
    int r = ei[e], c = ei[NE + e];
    csr[offs[c] + eseq[e]] = r;
}

// ---------------- pass A: s[c] = dinv_c*(sum f2a[csr].x + dinv_c x_c); unroll-8 ----------
__global__ void k_sg(const int* __restrict__ offs, const int* __restrict__ csr,
                     const float2* __restrict__ f2a, float2* __restrict__ sd) {
    int n = blockIdx.x * 256 + threadIdx.x;
    int a = offs[n], b = offs[n + 1];
    float2 me = f2a[n];
    float sum = me.x;
    for (int e = a; e < b; e += 8) {
#pragma unroll
        for (int i = 0; i < 8; i++) {
            int ee = e + i;
            int r = csr[min(ee, b - 1)];
            float v = f2a[r].x;
            sum += (ee < b) ? v : 0.0f;
        }
    }
    sd[n] = make_float2(me.y * sum, me.y);
}

// ================= FUSED: batched gather -> W2 MFMA -> relu -> segmented pool ============
// R12 single-edge loop (proven). aggs/x2s share one LDS buffer (temporally disjoint;
// barrier between block-wide aggs reads and x2s writes) -> 18.9 KB -> 8 blocks/CU.
__global__ __launch_bounds__(256) void k_gx2(
        const int* __restrict__ offs, const int* __restrict__ csr,
        const float2* __restrict__ sd, const float* __restrict__ W1,
        const float* __restrict__ b1, const unsigned short* __restrict__ W2T,
        const float* __restrict__ b2, const int* __restrict__ batch,
        float* __restrict__ sums) {
    __shared__ __align__(16) char smem[64 * 73 * 4];  // 18.7 KB shared by aggs & x2s
    __shared__ int bloc[64];
    unsigned short (*aggs)[72] = (unsigned short (*)[72])smem;  // phase 1-2a
    float (*x2s)[73] = (float (*)[73])smem;                     // phase 2b-3
    int t = threadIdx.x;
    int wv = t >> 6, lane = t & 63;
    int n0 = blockIdx.x * 64;
    int nw = n0 + wv * 16;
    if (t < 64) bloc[t] = batch[n0 + t];
    float w1j = W1[lane], b1j = b1[lane];
    int nl = nw + (lane & 15);
    int aL = offs[nl], bndL = offs[nl + 1];
    float2 sdL = sd[nl];

    int base   = __shfl(aL, 0, 64);     // offs[nw]
    int endAll = __shfl(bndL, 15, 64);  // offs[nw+16]

#define LOADB(dst, bs) do { int en = (bs) + lane;                        \
    dst = make_float2(0.0f, 0.0f);                                       \
    if (en < endAll) dst = sd[csr[en]]; } while (0)

    int bstart = base;
    float2 vcur, vnxt;
    LOADB(vcur, bstart);
    LOADB(vnxt, bstart + 64);

    for (int i = 0; i < 16; i++) {
        int a    = __shfl(aL, i, 64);
        int bnd  = __shfl(bndL, i, 64);
        float sx = __shfl(sdL.x, i, 64);
        float sy = __shfl(sdL.y, i, 64);
        float acc = sy * fmaxf(fmaf(sx, w1j, b1j), 0.0f);  // self-loop
        for (int e = a; e < bnd; ++e) {
            int slot = e - bstart;
            if (slot >= 64) {            // wave-uniform batch advance
                bstart += 64;
                slot -= 64;
                vcur = vnxt;
                LOADB(vnxt, bstart + 64);
            }
            float vx = __shfl(vcur.x, slot, 64);
            float vy = __shfl(vcur.y, slot, 64);
            acc = fmaf(vy, fmaxf(fmaf(vx, w1j, b1j), 0.0f), acc);
        }
        aggs[wv * 16 + i][lane] = f2bf(sy * acc);
    }
#undef LOADB

    __syncthreads();
    int lg = lane >> 4, lr = lane & 15;
    bf16x8 a0 = *reinterpret_cast<const bf16x8*>(&aggs[wv * 16 + lr][lg * 8]);
    bf16x8 a1 = *reinterpret_cast<const bf16x8*>(&aggs[wv * 16 + lr][32 + lg * 8]);
    __syncthreads();   // all aggs reads complete block-wide before x2s overwrites smem
    f32x4 acc4[4];
#pragma unroll
    for (int jt = 0; jt < 4; jt++) acc4[jt] = (f32x4){0.f, 0.f, 0.f, 0.f};
#pragma unroll
    for (int jt = 0; jt < 4; jt++) {
        bf16x8 b0 = *reinterpret_cast<const bf16x8*>(W2T + (jt * 16 + lr) * GH + lg * 8);
        bf16x8 b1v = *reinterpret_cast<const bf16x8*>(W2T + (jt * 16 + lr) * GH + 32 + lg * 8);
        acc4[jt] = __builtin_amdgcn_mfma_f32_16x16x32_bf16(a0, b0, acc4[jt], 0, 0, 0);
        acc4[jt] = __builtin_amdgcn_mfma_f32_16x16x32_bf16(a1, b1v, acc4[jt], 0, 0, 0);
    }
#pragma unroll
    for (int jt = 0; jt < 4; jt++) {
        float bj = b2[jt * 16 + lr];
#pragma unroll
        for (int r = 0; r < 4; r++)
            x2s[wv * 16 + lg * 4 + r][jt * 16 + lr] = fmaxf(acc4[jt][r] + bj, 0.0f);
    }
    __syncthreads();
    for (int i = wv; i < 64; i += 4) {
        bool isStart = (i == 0) || (bloc[i] != bloc[i - 1]);
        if (isStart) {
            int g = bloc[i];
            float s = 0.0f;
            int k = i;
            do { s += x2s[k][lane]; k++; } while (k < 64 && bloc[k] == g);
            atomicAdd(&sums[g * GH + lane], s);
        }
    }
}

// ---------------- per-graph: pooled = sums/cnt; gemb = pooled @ Wg + bg ----------------
__global__ void k_graph(const float* __restrict__ sums, const float* __restrict__ cnt,
                        const float* __restrict__ Wg, const float* __restrict__ bg,
                        float* __restrict__ gemb) {
    __shared__ float wgs[GH * GE];   // 32 KB
    __shared__ float ps[4 * GH];
    int t = threadIdx.x;
    for (int i = t; i < GH * GE; i += 256) wgs[i] = Wg[i];
    int gid = blockIdx.x * 256 + t;
    int g = gid >> 6, j = t & 63, w = t >> 6;
    float c = fmaxf(cnt[g], 1.0f);
    ps[t] = sums[g * GH + j] / c;
    __syncthreads();
    float o0 = bg[j], o1 = bg[GH + j];
#pragma unroll
    for (int k = 0; k < GH; k++) {
        float p = ps[w * GH + k];
        o0 = fmaf(p, wgs[k * GE + j], o0);
        o1 = fmaf(p, wgs[k * GE + GH + j], o1);
    }
    gemb[g * GE + j] = o0;
    gemb[g * GE + GH + j] = o1;
}

// ---------------- transpose+convert Wf1 -> WT bf16; block 1024 builds W2T ----------------
__global__ void k_wt(const float* __restrict__ Wf1, unsigned short* __restrict__ WT,
                     const float* __restrict__ W2, unsigned short* __restrict__ W2T) {
    if (blockIdx.x == 1024) {  // W2T[j][k] = bf16(W2[k][j]), 64x64
        int t = threadIdx.x;
        for (int i = 0; i < 16; i++) {
            int idx = t * 16 + i;
            int j = idx >> 6, k = idx & 63;
            W2T[j * GH + k] = f2bf(W2[k * GH + j]);
        }
        return;
    }
    __shared__ float tl[32][33];
    int bk = blockIdx.x & 127;
    int bn = blockIdx.x >> 7;
    int tx = threadIdx.x & 31, ty = threadIdx.x >> 5;  // 32 x 8
    int k0 = bk * 32, n0 = bn * 32;
#pragma unroll
    for (int i = 0; i < 4; i++) {
        int k = k0 + ty + i * 8;
        tl[ty + i * 8][tx] = (k < KD) ? Wf1[k * HIDD + n0 + tx] : 0.0f;
    }
    __syncthreads();
#pragma unroll
    for (int i = 0; i < 4; i++) {
        int n = n0 + ty + i * 8;
        WT[n * KP + k0 + tx] = f2bf(tl[tx][ty + i * 8]);
    }
}

// ---------------- build combined [NG][KP] bf16: guard-free paths for all pure regions ----
__global__ void k_comb(const float* __restrict__ gemb, const float* __restrict__ comp,
                       const float* __restrict__ prot, unsigned short* __restrict__ comb) {
    int idx = blockIdx.x * 256 + threadIdx.x;   // NG*512 threads, 8 elems each
    int g = idx >> 9;
    int k0 = (idx & 511) * 8;
    u16x8 r;
    float v[8];
    if (k0 + 8 <= GE) {                                   // pure gemb (boundary 8-aligned)
        __builtin_memcpy(v, gemb + (size_t)g * GE + k0, 32);
#pragma unroll
        for (int i = 0; i < 8; i++) r[i] = f2bf(v[i]);
    } else if (k0 >= GE && k0 + 8 <= GE + CDIM) {         // pure comp
        __builtin_memcpy(v, comp + (size_t)g * CDIM + (k0 - GE), 32);
#pragma unroll
        for (int i = 0; i < 8; i++) r[i] = f2bf(v[i]);
    } else if (k0 >= GE + CDIM && k0 + 8 <= KD) {         // pure prot
        __builtin_memcpy(v, prot + (size_t)g * PDIM + (k0 - GE - CDIM), 32);
#pragma unroll
        for (int i = 0; i < 8; i++) r[i] = f2bf(v[i]);
    } else if (k0 >= KD) {                                // pure pad
#pragma unroll
        for (int i = 0; i < 8; i++) r[i] = 0;
    } else {                                              // 2 straddling chunks per row
#pragma unroll
        for (int i = 0; i < 8; i++) {
            int k = k0 + i;
            float x = 0.0f;
            if (k < GE) x = gemb[g * GE + k];
            else if (k < GE + CDIM) x = comp[(size_t)g * CDIM + (k - GE)];
            else if (k < KD) x = prot[g * PDIM + (k - GE - CDIM)];
            r[i] = f2bf(x);
        }
    }
    *reinterpret_cast<u16x8*>(comb + (size_t)idx * 8) = r;
}

// ---------------- MFMA head GEMM: LDS-staged (R9-proven, 256n x 32g), BK=32, dbuf --------
typedef const __attribute__((address_space(1))) void gas_void;
typedef __attribute__((address_space(3))) void las_void;

__global__ __launch_bounds__(256) void k_gemm_mfma(
        const unsigned short* __restrict__ WT, const unsigned short* __restrict__ comb,
        const float* __restrict__ bf1, const float* __restrict__ Wf2,
        const float* __restrict__ bf2, float* __restrict__ out) {
    __shared__ unsigned short ldsA[2][256 * 32];  // 16 KB each
    __shared__ unsigned short ldsB[2][32 * 32];   // 2 KB each
    __shared__ float red[32];
    int t = threadIdx.x;
    int wv = t >> 6, lane = t & 63;
    int lg = lane >> 4, lr = lane & 15;
    int g0 = blockIdx.x * 32;
    int nbase = wv * 64;

    int rowp = lane >> 2;        // 0..15 (row within 16-row staging chunk)
    int kp = (lane & 3) * 8;     // 0,8,16,24 (k within 32-k step)

    if (t < 32) red[t] = 0.0f;

    f32x4 acc[4][2];
#pragma unroll
    for (int i = 0; i < 4; i++)
#pragma unroll
        for (int j = 0; j < 2; j++) acc[i][j] = (f32x4){0.f, 0.f, 0.f, 0.f};

#define STAGE(buf, k0) do {                                                                  \
    _Pragma("unroll")                                                                        \
    for (int i = 0; i < 4; i++)                                                              \
        __builtin_amdgcn_global_load_lds(                                                    \
            (gas_void*)(WT + (size_t)(wv * 64 + i * 16 + rowp) * KP + (k0) + kp),            \
            (las_void*)(&ldsA[buf][(wv * 64 + i * 16) * 32]), 16, 0, 0);                     \
    if (wv < 2)                                                                              \
        __builtin_amdgcn_global_load_lds(                                                    \
            (gas_void*)(comb + (size_t)(g0 + wv * 16 + rowp) * KP + (k0) + kp),              \
            (las_void*)(&ldsB[buf][(wv * 16) * 32]), 16, 0, 0);                              \
} while (0)

    STAGE(0, 0);
    __syncthreads();
#pragma unroll 1
    for (int s = 0; s < 128; ++s) {
        int cur = s & 1;
        if (s < 127) STAGE(cur ^ 1, (s + 1) * 32);
        bf16x8 a[4], b[2];
#pragma unroll
        for (int nt = 0; nt < 4; nt++)
            a[nt] = *reinterpret_cast<const bf16x8*>(&ldsA[cur][(nbase + nt * 16 + lr) * 32 + lg * 8]);
#pragma unroll
        for (int gt = 0; gt < 2; gt++)
            b[gt] = *reinterpret_cast<const bf16x8*>(&ldsB[cur][(gt * 16 + lr) * 32 + lg * 8]);
#pragma unroll
        for (int nt = 0; nt < 4; nt++)
#pragma unroll
            for (int gt = 0; gt < 2; gt++)
                acc[nt][gt] = __builtin_amdgcn_mfma_f32_16x16x32_bf16(a[nt], b[gt], acc[nt][gt], 0, 0, 0);
        __syncthreads();  // drains staging (vmcnt) + frag reads before buffer reuse
    }
#undef STAGE

    float bf2c = bf2[0];
#pragma unroll
    for (int gt = 0; gt < 2; gt++) {
        float pv = 0.0f;
#pragma unroll
        for (int nt = 0; nt < 4; nt++) {
            int nb = nbase + nt * 16 + lg * 4;
#pragma unroll
            for (int r = 0; r < 4; r++) {
                float h = fmaxf(acc[nt][gt][r] + bf1[nb + r], 0.0f);
                pv = fmaf(h, Wf2[nb + r], pv);
            }
        }
        pv += __shfl_xor(pv, 16);
        pv += __shfl_xor(pv, 32);
        if (lane < 16) atomicAdd(&red[gt * 16 + lane], pv);
    }
    __syncthreads();
    if (t < 32) out[g0 + t] = 1.0f / (1.0f + expf(-(red[t] + bf2c)));
}

extern "C" void kernel_launch(void* const* d_in, const int* in_sizes, int n_in,
                              void* d_out, int out_size, void* d_ws, size_t ws_size,
                              hipStream_t stream) {
    const float* node_x = (const float*)d_in[0];
    const float* comp   = (const float*)d_in[1];
    const float* prot   = (const float*)d_in[2];
    const int*   ei     = (const int*)d_in[3];
    const int*   batch  = (const int*)d_in[4];
    const float* W1  = (const float*)d_in[5];
    const float* b1  = (const float*)d_in[6];
    const float* W2  = (const float*)d_in[7];
    const float* b2  = (const float*)d_in[8];
    const float* Wg  = (const float*)d_in[9];
    const float* bg  = (const float*)d_in[10];
    const float* Wf1 = (const float*)d_in[11];
    const float* bf1 = (const float*)d_in[12];
    const float* Wf2 = (const float*)d_in[13];
    const float* bf2 = (const float*)d_in[14];
    float* out = (float*)d_out;

    // -------- workspace layout (region A [0,134MB) becomes comb at k_comb) ----------------
    char* W = (char*)d_ws;
    unsigned short* comb = (unsigned short*)W;
    int*    idg     = (int*)(W + 0);            // NN int (edge counts; dead after k_prep)
    float2* f2a     = (float2*)(W + 2097152);   // NN float2
    float2* sd      = (float2*)(W + 6291456);   // NN float2
    int*    ecnt    = (int*)(W + 10485760);     // NN int
    int*    offs    = (int*)(W + 12582912);     // NN+1 int
    int*    bsum    = (int*)(W + 16777728);     // 2048 int
    int*    csr     = (int*)(W + 16786432);     // NE int
    float*  sums    = (float*)(W + 25175040);   // NG*64 f32
    float*  cnt     = (float*)(W + 29369344);   // NG f32
    int*    eseq    = (int*)(W + 33554432);     // NE int (within-node slot)
    // Region B/C (live to the end):
    float*  gemb    = (float*)(W + 134217728);              // NG*128 f32
    unsigned short* WT  = (unsigned short*)(W + 142606336); // 256*KP bf16
    unsigned short* W2T = (unsigned short*)(W + 144703488); // 64*64 bf16

    k_init<<<4096, 256, 0, stream>>>(idg, sums);
    k_wt<<<1025, 256, 0, stream>>>(Wf1, WT, W2, W2T);  // FIRST: W2T/WT ready before use
    k_deg<<<NE / 256, 256, 0, stream>>>(ei, idg, eseq);
    k_prep<<<NN / 256, 256, 0, stream>>>(node_x, idg, f2a, ecnt);
    k_cnt<<<NG / 256, 256, 0, stream>>>(batch, cnt);
    k_scan1<<<NN / 256, 256, 0, stream>>>(ecnt, bsum);
    k_scan2<<<1, 256, 0, stream>>>(bsum);
    k_scan3<<<NN / 256, 256, 0, stream>>>(ecnt, bsum, offs);
    k_fill<<<NE / 256, 256, 0, stream>>>(ei, offs, eseq, csr);
    k_sg<<<NN / 256, 256, 0, stream>>>(offs, csr, f2a, sd);
    k_gx2<<<NN / 64, 256, 0, stream>>>(offs, csr, sd, W1, b1, W2T, b2, batch, sums);
    k_graph<<<NG * GH / 256, 256, 0, stream>>>(sums, cnt, Wg, bg, gemb);
    k_comb<<<NG * 512 / 256, 256, 0, stream>>>(gemb, comp, prot, comb);
    k_gemm_mfma<<<NG / 32, 256, 0, stream>>>(WT, comb, bf1, Wf2, bf2, out);
}